// Round 1
// 1385.455 us; speedup vs baseline: 1.4840x; 1.4840x over previous
//
#include <hip/hip_runtime.h>
#include <math.h>
#include <stdint.h>

// Problem constants
#define B_ 512
#define D_ 1024
#define H_ 1024
#define T_ 48
#define NG 4096      // 4*H gate columns

typedef _Float16 half8 __attribute__((ext_vector_type(8)));
typedef float f32x4 __attribute__((ext_vector_type(4)));

// Async global->LDS, 16B per lane. LDS dest must be wave-uniform base; HW adds lane*16.
__device__ __forceinline__ void cp16(const void* g, void* l) {
  __builtin_amdgcn_global_load_lds(
      (__attribute__((address_space(1))) const unsigned int*)(uintptr_t)g,
      (__attribute__((address_space(3))) unsigned int*)(uintptr_t)l, 16, 0, 0);
}

__device__ __forceinline__ float sigmoidf_(float x) { return 1.0f / (1.0f + expf(-x)); }

// ---------------------------------------------------------------------------
// Prep: Wx1[j][k]=W_ih[j][k] (k<1024), Whh[j][k]=W_hh[j][k], Wp[j][k]=W_ih[j][1024+k]
// all f16. 3 * 4096*1024 = 12,582,912 elements -> 49152 blocks of 256.
// ---------------------------------------------------------------------------
__global__ void prep_w(const float* __restrict__ W_ih, const float* __restrict__ W_hh,
                       _Float16* __restrict__ Wx1, _Float16* __restrict__ Whh,
                       _Float16* __restrict__ Wp) {
  int idx = blockIdx.x * 256 + threadIdx.x;
  const int n1 = NG * H_;  // 4,194,304
  if (idx < n1) {
    int j = idx >> 10, k = idx & 1023;
    Wx1[idx] = (_Float16)W_ih[j * 2048 + k];
  } else if (idx < 2 * n1) {
    int i2 = idx - n1;
    Whh[i2] = (_Float16)W_hh[i2];
  } else {
    int i3 = idx - 2 * n1;
    int j = i3 >> 10, k = i3 & 1023;
    Wp[i3] = (_Float16)W_ih[j * 2048 + 1024 + k];
  }
}

// ---------------------------------------------------------------------------
// Pool: pooled[b][d] = sum_t mask(t,b)*dh[t][b][d] / sum_t mask(t,b); also dh->f16 (t>=1)
// ---------------------------------------------------------------------------
__global__ void pool_conv(const float* __restrict__ dh, const int* __restrict__ caps,
                          _Float16* __restrict__ dh16, _Float16* __restrict__ pooled16) {
  int tid = blockIdx.x * 256 + threadIdx.x;  // b*1024 + d, < 524288
  int b = tid >> 10;
  float sum = 0.0f, cnt = 0.0f;
  for (int t = 0; t < T_; ++t) {
    int cap = caps[t * B_ + b];
    float v = dh[(size_t)t * (B_ * D_) + tid];
    if (cap != 0 && cap != 2) { sum += v; cnt += 1.0f; }
    if (t >= 1) dh16[(size_t)t * (B_ * D_) + tid] = (_Float16)v;
  }
  pooled16[tid] = (_Float16)(sum / cnt);
}

// ---------------------------------------------------------------------------
// Init: hA=0, c=0, feats[:,0,:]=0
// ---------------------------------------------------------------------------
__global__ void init_zero(_Float16* __restrict__ hA, float* __restrict__ c,
                          float* __restrict__ out) {
  int tid = blockIdx.x * 256 + threadIdx.x;  // < 524288
  hA[tid] = (_Float16)0.0f;
  c[tid] = 0.0f;
  int b = tid >> 10, d = tid & 1023;
  out[(size_t)b * (T_ * H_) + d] = 0.0f;
}

// ---------------------------------------------------------------------------
// Xc[b][n] = sum_k pooled[b][k]*Wp[n][k] + b_ih[n] + b_hh[n]   (f32, B x 4096)
// 64x128 tile, 4 waves in 2x2, each wave 32x64 (2 m-tiles x 4 n-tiles of 16x16)
// ---------------------------------------------------------------------------
__global__ __launch_bounds__(256) void gemm_pool(
    const _Float16* __restrict__ A, const _Float16* __restrict__ Wp,
    const float* __restrict__ b_ih, const float* __restrict__ b_hh,
    float* __restrict__ Xc) {
  __shared__ __align__(16) _Float16 sA[64 * 32];
  __shared__ __align__(16) _Float16 sB[128 * 32];
  const int tid = threadIdx.x;
  const int wave = tid >> 6, lane = tid & 63;
  const int quad = lane >> 4, l16 = lane & 15;
  const int wm = wave & 1, wn = wave >> 1;
  const int n0 = blockIdx.x * 128;
  const int b0 = blockIdx.y * 64;
  const int rS = tid >> 2, cS = tid & 3;

  f32x4 acc[2][4] = {};
  for (int k0 = 0; k0 < 1024; k0 += 32) {
    cp16(A + (size_t)(b0 + rS) * 1024 + k0 + cS * 8, sA + wave * 512);
    cp16(Wp + (size_t)(n0 + rS) * 1024 + k0 + cS * 8, sB + wave * 512);
    cp16(Wp + (size_t)(n0 + 64 + rS) * 1024 + k0 + cS * 8, sB + 2048 + wave * 512);
    __syncthreads();
    half8 a[2], bfr[4];
#pragma unroll
    for (int m = 0; m < 2; ++m)
      a[m] = *(const half8*)(sA + (wm * 32 + m * 16 + l16) * 32 + quad * 8);
#pragma unroll
    for (int n = 0; n < 4; ++n)
      bfr[n] = *(const half8*)(sB + (wn * 64 + n * 16 + l16) * 32 + quad * 8);
#pragma unroll
    for (int m = 0; m < 2; ++m)
#pragma unroll
      for (int n = 0; n < 4; ++n)
        acc[m][n] = __builtin_amdgcn_mfma_f32_16x16x32_f16(a[m], bfr[n], acc[m][n], 0, 0, 0);
    __syncthreads();
  }
#pragma unroll
  for (int m = 0; m < 2; ++m) {
#pragma unroll
    for (int n = 0; n < 4; ++n) {
      int nn = n0 + wn * 64 + n * 16 + l16;
      float bias = b_ih[nn] + b_hh[nn];
#pragma unroll
      for (int r = 0; r < 4; ++r) {
        int bb = b0 + wm * 32 + m * 16 + quad * 4 + r;
        Xc[(size_t)bb * NG + nn] = acc[m][n][r] + bias;
      }
    }
  }
}

// ---------------------------------------------------------------------------
// Big input-projection GEMM (hoisted out of the recurrence):
//   Xall[r][n] (f16) = sum_k A[r][k]*Wx1[n][k] + Xc[r&511][n]
// A = dh16 rows for t=1..47 (contiguous), M=24064, N=4096, K=1024.
// m97-proven structure: 128x128 tile, 4 waves 2x2 each 64x64 (4x4 frags),
// K-step 32, + 2-phase double-buffered LDS (prefetch next K-slice while
// computing current; single barrier per iter).
// ---------------------------------------------------------------------------
__global__ __launch_bounds__(256) void gemm_x(
    const _Float16* __restrict__ A, const _Float16* __restrict__ Bw,
    const float* __restrict__ Xc, _Float16* __restrict__ Xall) {
  __shared__ __align__(16) _Float16 sA[2][128 * 32];
  __shared__ __align__(16) _Float16 sB[2][128 * 32];
  const int tid = threadIdx.x;
  const int wave = tid >> 6, lane = tid & 63;
  const int quad = lane >> 4, l16 = lane & 15;
  const int wm = wave & 1, wn = wave >> 1;
  const int n0 = blockIdx.x * 128;
  const int m0 = blockIdx.y * 128;
  const int rS = tid >> 2, cS = tid & 3;

  const _Float16* aR0 = A + (size_t)(m0 + rS) * 1024 + cS * 8;
  const _Float16* aR1 = A + (size_t)(m0 + 64 + rS) * 1024 + cS * 8;
  const _Float16* bR0 = Bw + (size_t)(n0 + rS) * 1024 + cS * 8;
  const _Float16* bR1 = Bw + (size_t)(n0 + 64 + rS) * 1024 + cS * 8;

  f32x4 acc[4][4] = {};

  auto stage = [&](int buf, int k0) {
    cp16(aR0 + k0, &sA[buf][wave * 512]);
    cp16(aR1 + k0, &sA[buf][2048 + wave * 512]);
    cp16(bR0 + k0, &sB[buf][wave * 512]);
    cp16(bR1 + k0, &sB[buf][2048 + wave * 512]);
  };
  auto compute = [&](int cur) {
    half8 a[4], b[4];
#pragma unroll
    for (int m = 0; m < 4; ++m)
      a[m] = *(const half8*)&sA[cur][(wm * 64 + m * 16 + l16) * 32 + quad * 8];
#pragma unroll
    for (int n = 0; n < 4; ++n)
      b[n] = *(const half8*)&sB[cur][(wn * 64 + n * 16 + l16) * 32 + quad * 8];
#pragma unroll
    for (int m = 0; m < 4; ++m)
#pragma unroll
      for (int n = 0; n < 4; ++n)
        acc[m][n] = __builtin_amdgcn_mfma_f32_16x16x32_f16(a[m], b[n], acc[m][n], 0, 0, 0);
  };

  stage(0, 0);
  __syncthreads();
  for (int it = 0; it < 31; ++it) {
    const int cur = it & 1;
    stage(cur ^ 1, (it + 1) * 32);  // in flight across the barrier-drain of THIS iter
    compute(cur);
    __syncthreads();  // drains vmcnt (next buf ready) + all reads of cur done
  }
  compute(1);  // it=31

#pragma unroll
  for (int m = 0; m < 4; ++m) {
#pragma unroll
    for (int n = 0; n < 4; ++n) {
      const int col = n0 + wn * 64 + n * 16 + l16;
#pragma unroll
      for (int r = 0; r < 4; ++r) {
        const int row = m0 + wm * 64 + m * 16 + quad * 4 + r;
        Xall[(size_t)row * NG + col] =
            (_Float16)(acc[m][n][r] + Xc[(size_t)(row & 511) * NG + col]);
      }
    }
  }
}

// ---------------------------------------------------------------------------
// One LSTM step (recurrent part only): gates = h_prev @ Whh^T + Xall[t], cell update.
// K=1024 now (input projection precomputed). Latency-optimized:
//   - K-step 64 -> 16 iters
//   - double-buffered LDS, single-barrier 2-phase (prefetch overlaps MFMA)
//   - XOR swizzle (chunk ^= row&7 on 16B granules): linear LDS dest (cp16
//     requirement), pre-swizzled GLOBAL source, swizzled ds_read -> the
//     stride-128B row reads become bank-conflict-free.
// Block: 64 batch rows x 32 hidden cols x 4 gates; 4 waves 2x2; grid (32,8).
// ---------------------------------------------------------------------------
__global__ __launch_bounds__(256) void lstm_step(
    const _Float16* __restrict__ Whh, const _Float16* __restrict__ Xall,
    const _Float16* __restrict__ h_prev, _Float16* __restrict__ h_next,
    float* __restrict__ c, float* __restrict__ out, int t) {
  __shared__ __align__(16) _Float16 sA[2][64 * 64];    // 2 x 8 KB
  __shared__ __align__(16) _Float16 sB[2][128 * 64];   // 2 x 16 KB
  const int tid = threadIdx.x;
  const int wave = tid >> 6, lane = tid & 63;
  const int quad = lane >> 4, l16 = lane & 15;
  const int wm = wave & 1, wn = wave >> 1;
  const int j0 = blockIdx.x * 32;   // hidden-col group
  const int b0 = blockIdx.y * 64;   // batch rows
  const int rS = tid >> 3;          // 0..31 (row within 32-row issue group)
  const int cS = tid & 7;           // 16B chunk 0..7 within the 128B row
  const int csw = (cS ^ (rS & 7)) * 8;  // pre-swizzled source chunk (halfs)

  // B rows: gate-interleaved so each wave's 4 n-tiles are gates i,f,g,o.
  // LDS row s (0..127): gate=(s>>4)&3, col=j0+(s&15)+((s&64)?16:0)
  int jr[4];
#pragma unroll
  for (int i = 0; i < 4; ++i) {
    int s = i * 32 + rS;
    jr[i] = (((s >> 4) & 3) << 10) + j0 + (s & 15) + ((s & 64) ? 16 : 0);
  }
  const _Float16* aRow0 = h_prev + (size_t)(b0 + rS) * 1024 + csw;
  const _Float16* aRow1 = h_prev + (size_t)(b0 + 32 + rS) * 1024 + csw;

  f32x4 acc[2][4] = {};

  auto stage = [&](int buf, int k0) {
    cp16(aRow0 + k0, &sA[buf][wave * 512]);
    cp16(aRow1 + k0, &sA[buf][2048 + wave * 512]);
    cp16(Whh + (size_t)jr[0] * 1024 + k0 + csw, &sB[buf][wave * 512]);
    cp16(Whh + (size_t)jr[1] * 1024 + k0 + csw, &sB[buf][2048 + wave * 512]);
    cp16(Whh + (size_t)jr[2] * 1024 + k0 + csw, &sB[buf][4096 + wave * 512]);
    cp16(Whh + (size_t)jr[3] * 1024 + k0 + csw, &sB[buf][6144 + wave * 512]);
  };
  auto compute = [&](int cur) {
    half8 a[2][2], bfr[2][4];
#pragma unroll
    for (int kk = 0; kk < 2; ++kk) {
#pragma unroll
      for (int m = 0; m < 2; ++m) {
        int row = wm * 32 + m * 16 + l16;
        int ch = ((kk * 4 + quad) ^ (row & 7)) * 8;
        a[kk][m] = *(const half8*)&sA[cur][row * 64 + ch];
      }
#pragma unroll
      for (int n = 0; n < 4; ++n) {
        int row = wn * 64 + n * 16 + l16;
        int ch = ((kk * 4 + quad) ^ (row & 7)) * 8;
        bfr[kk][n] = *(const half8*)&sB[cur][row * 64 + ch];
      }
    }
#pragma unroll
    for (int kk = 0; kk < 2; ++kk)
#pragma unroll
      for (int m = 0; m < 2; ++m)
#pragma unroll
        for (int n = 0; n < 4; ++n)
          acc[m][n] =
              __builtin_amdgcn_mfma_f32_16x16x32_f16(a[kk][m], bfr[kk][n], acc[m][n], 0, 0, 0);
  };

  stage(0, 0);
  __syncthreads();
  for (int it = 0; it < 15; ++it) {
    const int cur = it & 1;
    stage(cur ^ 1, (it + 1) * 64);
    compute(cur);
    __syncthreads();
  }
  compute(1);  // it=15

  // Epilogue: acc[m][0..3] = i,f,g,o partials; add precomputed Xall[t] slice.
  const int col = j0 + wn * 16 + l16;
  const _Float16* xrow = Xall + (size_t)(t - 1) * 512 * NG;
#pragma unroll
  for (int m = 0; m < 2; ++m) {
#pragma unroll
    for (int r = 0; r < 4; ++r) {
      int bb = b0 + wm * 32 + m * 16 + quad * 4 + r;
      const _Float16* xb = xrow + (size_t)bb * NG + col;
      float iv = acc[m][0][r] + (float)xb[0];
      float fv = acc[m][1][r] + (float)xb[1024];
      float gv = acc[m][2][r] + (float)xb[2048];
      float ov = acc[m][3][r] + (float)xb[3072];
      float ig = sigmoidf_(iv), fg = sigmoidf_(fv), og = sigmoidf_(ov);
      float gg = tanhf(gv);
      size_t ci = (size_t)bb * H_ + col;
      float cn = fg * c[ci] + ig * gg;
      c[ci] = cn;
      float hv = og * tanhf(cn);
      h_next[ci] = (_Float16)hv;
      out[(size_t)bb * (T_ * H_) + (size_t)t * H_ + col] = hv;
    }
  }
}

// ---------------------------------------------------------------------------
extern "C" void kernel_launch(void* const* d_in, const int* in_sizes, int n_in,
                              void* d_out, int out_size, void* d_ws, size_t ws_size,
                              hipStream_t stream) {
  (void)in_sizes; (void)n_in; (void)out_size; (void)ws_size;
  const float* dh   = (const float*)d_in[0];
  // d_in[1] ("outputs") is unused by the reference
  const int*   caps = (const int*)d_in[2];
  const float* W_ih = (const float*)d_in[3];
  const float* W_hh = (const float*)d_in[4];
  const float* b_ih = (const float*)d_in[5];
  const float* b_hh = (const float*)d_in[6];
  float* out = (float*)d_out;

  // Workspace layout (~286 MB total — main risk if ws_size is smaller):
  char* ws = (char*)d_ws;
  _Float16* Wx116 = (_Float16*)(ws);                 //   8,388,608
  _Float16* Whh16 = (_Float16*)(ws + 8388608);       //   8,388,608
  _Float16* Wp    = (_Float16*)(ws + 16777216);      //   8,388,608
  _Float16* dh16  = (_Float16*)(ws + 25165824);      //  50,331,648
  _Float16* pld16 = (_Float16*)(ws + 75497472);      //   1,048,576
  float*    Xc    = (float*)   (ws + 76546048);      //   8,388,608
  _Float16* Xall  = (_Float16*)(ws + 84934656);      // 197,132,288 (47*512*4096 f16)
  _Float16* hA    = (_Float16*)(ws + 282066944);     //   1,048,576
  _Float16* hB    = (_Float16*)(ws + 283115520);     //   1,048,576
  float*    c     = (float*)   (ws + 284164096);     //   2,097,152  (end ~286.3 MB)

  prep_w<<<49152, 256, 0, stream>>>(W_ih, W_hh, Wx116, Whh16, Wp);
  pool_conv<<<2048, 256, 0, stream>>>(dh, caps, dh16, pld16);
  init_zero<<<2048, 256, 0, stream>>>(hA, c, out);
  gemm_pool<<<dim3(32, 8), 256, 0, stream>>>(pld16, Wp, b_ih, b_hh, Xc);
  // A = dh16 rows from t=1 onward: dh16 + 512*1024 elements, [24064 x 1024] f16
  gemm_x<<<dim3(32, 188), 256, 0, stream>>>(dh16 + 524288, Wx116, Xc, Xall);
  for (int t = 1; t < T_; ++t) {
    const _Float16* hp = (t & 1) ? hA : hB;
    _Float16*       hn = (t & 1) ? hB : hA;
    lstm_step<<<dim3(32, 8), 256, 0, stream>>>(Whh16, Xall, hp, hn, c, out, t);
  }
}

// Round 2
// 1156.184 us; speedup vs baseline: 1.7783x; 1.1983x over previous
//
#include <hip/hip_runtime.h>
#include <math.h>
#include <stdint.h>

// Problem constants
#define B_ 512
#define D_ 1024
#define H_ 1024
#define T_ 48
#define NG 4096      // 4*H gate columns

typedef _Float16 half8 __attribute__((ext_vector_type(8)));
typedef float f32x4 __attribute__((ext_vector_type(4)));

// Async global->LDS, 16B per lane. LDS dest must be wave-uniform base; HW adds lane*16.
__device__ __forceinline__ void cp16(const void* g, void* l) {
  __builtin_amdgcn_global_load_lds(
      (__attribute__((address_space(1))) const unsigned int*)(uintptr_t)g,
      (__attribute__((address_space(3))) unsigned int*)(uintptr_t)l, 16, 0, 0);
}

__device__ __forceinline__ float sigmoidf_(float x) { return 1.0f / (1.0f + expf(-x)); }

// ---------------------------------------------------------------------------
// Prep: Wx1[j][k]=W_ih[j][k] (k<1024), Whh[j][k]=W_hh[j][k], Wp[j][k]=W_ih[j][1024+k]
// ---------------------------------------------------------------------------
__global__ void prep_w(const float* __restrict__ W_ih, const float* __restrict__ W_hh,
                       _Float16* __restrict__ Wx1, _Float16* __restrict__ Whh,
                       _Float16* __restrict__ Wp) {
  int idx = blockIdx.x * 256 + threadIdx.x;
  const int n1 = NG * H_;  // 4,194,304
  if (idx < n1) {
    int j = idx >> 10, k = idx & 1023;
    Wx1[idx] = (_Float16)W_ih[j * 2048 + k];
  } else if (idx < 2 * n1) {
    int i2 = idx - n1;
    Whh[i2] = (_Float16)W_hh[i2];
  } else {
    int i3 = idx - 2 * n1;
    int j = i3 >> 10, k = i3 & 1023;
    Wp[i3] = (_Float16)W_ih[j * 2048 + 1024 + k];
  }
}

// ---------------------------------------------------------------------------
// Pool: pooled[b][d] = sum_t mask(t,b)*dh[t][b][d] / sum_t mask(t,b); also dh->f16 (t>=1)
// ---------------------------------------------------------------------------
__global__ void pool_conv(const float* __restrict__ dh, const int* __restrict__ caps,
                          _Float16* __restrict__ dh16, _Float16* __restrict__ pooled16) {
  int tid = blockIdx.x * 256 + threadIdx.x;  // b*1024 + d, < 524288
  int b = tid >> 10;
  float sum = 0.0f, cnt = 0.0f;
  for (int t = 0; t < T_; ++t) {
    int cap = caps[t * B_ + b];
    float v = dh[(size_t)t * (B_ * D_) + tid];
    if (cap != 0 && cap != 2) { sum += v; cnt += 1.0f; }
    if (t >= 1) dh16[(size_t)t * (B_ * D_) + tid] = (_Float16)v;
  }
  pooled16[tid] = (_Float16)(sum / cnt);
}

// ---------------------------------------------------------------------------
// Init: hA=0, c=0, feats[:,0,:]=0
// ---------------------------------------------------------------------------
__global__ void init_zero(_Float16* __restrict__ hA, float* __restrict__ c,
                          float* __restrict__ out) {
  int tid = blockIdx.x * 256 + threadIdx.x;  // < 524288
  hA[tid] = (_Float16)0.0f;
  c[tid] = 0.0f;
  int b = tid >> 10, d = tid & 1023;
  out[(size_t)b * (T_ * H_) + d] = 0.0f;
}

// ---------------------------------------------------------------------------
// Xc[b][n] = sum_k pooled[b][k]*Wp[n][k] + b_ih[n] + b_hh[n]   (f32, B x 4096)
// ---------------------------------------------------------------------------
__global__ __launch_bounds__(256) void gemm_pool(
    const _Float16* __restrict__ A, const _Float16* __restrict__ Wp,
    const float* __restrict__ b_ih, const float* __restrict__ b_hh,
    float* __restrict__ Xc) {
  __shared__ __align__(16) _Float16 sA[64 * 32];
  __shared__ __align__(16) _Float16 sB[128 * 32];
  const int tid = threadIdx.x;
  const int wave = tid >> 6, lane = tid & 63;
  const int quad = lane >> 4, l16 = lane & 15;
  const int wm = wave & 1, wn = wave >> 1;
  const int n0 = blockIdx.x * 128;
  const int b0 = blockIdx.y * 64;
  const int rS = tid >> 2, cS = tid & 3;

  f32x4 acc[2][4] = {};
  for (int k0 = 0; k0 < 1024; k0 += 32) {
    cp16(A + (size_t)(b0 + rS) * 1024 + k0 + cS * 8, sA + wave * 512);
    cp16(Wp + (size_t)(n0 + rS) * 1024 + k0 + cS * 8, sB + wave * 512);
    cp16(Wp + (size_t)(n0 + 64 + rS) * 1024 + k0 + cS * 8, sB + 2048 + wave * 512);
    __syncthreads();
    half8 a[2], bfr[4];
#pragma unroll
    for (int m = 0; m < 2; ++m)
      a[m] = *(const half8*)(sA + (wm * 32 + m * 16 + l16) * 32 + quad * 8);
#pragma unroll
    for (int n = 0; n < 4; ++n)
      bfr[n] = *(const half8*)(sB + (wn * 64 + n * 16 + l16) * 32 + quad * 8);
#pragma unroll
    for (int m = 0; m < 2; ++m)
#pragma unroll
      for (int n = 0; n < 4; ++n)
        acc[m][n] = __builtin_amdgcn_mfma_f32_16x16x32_f16(a[m], bfr[n], acc[m][n], 0, 0, 0);
    __syncthreads();
  }
#pragma unroll
  for (int m = 0; m < 2; ++m) {
#pragma unroll
    for (int n = 0; n < 4; ++n) {
      int nn = n0 + wn * 64 + n * 16 + l16;
      float bias = b_ih[nn] + b_hh[nn];
#pragma unroll
      for (int r = 0; r < 4; ++r) {
        int bb = b0 + wm * 32 + m * 16 + quad * 4 + r;
        Xc[(size_t)bb * NG + nn] = acc[m][n][r] + bias;
      }
    }
  }
}

// ---------------------------------------------------------------------------
// Big input-projection GEMM (hoisted out of the recurrence):
//   Xall[r][n] (f16) = sum_k A[r][k]*Wx1[n][k] + Xc[r&511][n]
// M=24064, N=4096, K=1024. 128x128 tile, 2-phase double-buffered LDS.
// (Unchanged this round; 8-phase port is the next candidate.)
// ---------------------------------------------------------------------------
__global__ __launch_bounds__(256) void gemm_x(
    const _Float16* __restrict__ A, const _Float16* __restrict__ Bw,
    const float* __restrict__ Xc, _Float16* __restrict__ Xall) {
  __shared__ __align__(16) _Float16 sA[2][128 * 32];
  __shared__ __align__(16) _Float16 sB[2][128 * 32];
  const int tid = threadIdx.x;
  const int wave = tid >> 6, lane = tid & 63;
  const int quad = lane >> 4, l16 = lane & 15;
  const int wm = wave & 1, wn = wave >> 1;
  const int n0 = blockIdx.x * 128;
  const int m0 = blockIdx.y * 128;
  const int rS = tid >> 2, cS = tid & 3;

  const _Float16* aR0 = A + (size_t)(m0 + rS) * 1024 + cS * 8;
  const _Float16* aR1 = A + (size_t)(m0 + 64 + rS) * 1024 + cS * 8;
  const _Float16* bR0 = Bw + (size_t)(n0 + rS) * 1024 + cS * 8;
  const _Float16* bR1 = Bw + (size_t)(n0 + 64 + rS) * 1024 + cS * 8;

  f32x4 acc[4][4] = {};

  auto stage = [&](int buf, int k0) {
    cp16(aR0 + k0, &sA[buf][wave * 512]);
    cp16(aR1 + k0, &sA[buf][2048 + wave * 512]);
    cp16(bR0 + k0, &sB[buf][wave * 512]);
    cp16(bR1 + k0, &sB[buf][2048 + wave * 512]);
  };
  auto compute = [&](int cur) {
    half8 a[4], b[4];
#pragma unroll
    for (int m = 0; m < 4; ++m)
      a[m] = *(const half8*)&sA[cur][(wm * 64 + m * 16 + l16) * 32 + quad * 8];
#pragma unroll
    for (int n = 0; n < 4; ++n)
      b[n] = *(const half8*)&sB[cur][(wn * 64 + n * 16 + l16) * 32 + quad * 8];
#pragma unroll
    for (int m = 0; m < 4; ++m)
#pragma unroll
      for (int n = 0; n < 4; ++n)
        acc[m][n] = __builtin_amdgcn_mfma_f32_16x16x32_f16(a[m], b[n], acc[m][n], 0, 0, 0);
  };

  stage(0, 0);
  __syncthreads();
  for (int it = 0; it < 31; ++it) {
    const int cur = it & 1;
    stage(cur ^ 1, (it + 1) * 32);
    compute(cur);
    __syncthreads();
  }
  compute(1);  // it=31

#pragma unroll
  for (int m = 0; m < 4; ++m) {
#pragma unroll
    for (int n = 0; n < 4; ++n) {
      const int col = n0 + wn * 64 + n * 16 + l16;
#pragma unroll
      for (int r = 0; r < 4; ++r) {
        const int row = m0 + wm * 64 + m * 16 + quad * 4 + r;
        Xall[(size_t)row * NG + col] =
            (_Float16)(acc[m][n][r] + Xc[(size_t)(row & 511) * NG + col]);
      }
    }
  }
}

// ---------------------------------------------------------------------------
// One LSTM step, K-SPLIT: 512 threads = 2 wave-groups of 4 waves.
// Group g computes K in [512g, 512g+512) of the same 64x128 tile into its own
// double-buffered LDS (8 iters of K-step 64), XOR-swizzled as before.
// Then group1 writes f32 partials to LDS (bank-swizzled), group0 adds and
// runs the epilogue. Occupancy: 8 waves/block, 1 block/CU = 2 waves/SIMD
// (vs 1 before) -> latency hiding; K-chain halved (16 -> 8 iters).
// T14: group0 issues the scattered Xall/c epilogue loads BEFORE the K-loop.
// ---------------------------------------------------------------------------
__global__ __launch_bounds__(512, 2) void lstm_step(
    const _Float16* __restrict__ Whh, const _Float16* __restrict__ Xall,
    const _Float16* __restrict__ h_prev, _Float16* __restrict__ h_next,
    float* __restrict__ c, float* __restrict__ out, int t) {
  __shared__ __align__(16) _Float16 sA[2][2][64 * 64];    // [grp][buf], 32 KB
  __shared__ __align__(16) _Float16 sB[2][2][128 * 64];   // [grp][buf], 64 KB
  const int tid = threadIdx.x;
  const int grp = tid >> 8;        // wave-group 0/1 (K-split)
  const int gt = tid & 255;
  const int wave = gt >> 6, lane = gt & 63;
  const int quad = lane >> 4, l16 = lane & 15;
  const int wm = wave & 1, wn = wave >> 1;
  const int j0 = blockIdx.x * 32;   // hidden-col group
  const int b0 = blockIdx.y * 64;   // batch rows
  const int rS = gt >> 3;           // 0..31 (row within 32-row issue group)
  const int cS = gt & 7;            // 16B chunk 0..7 within the 128B row
  const int csw = (cS ^ (rS & 7)) * 8;  // pre-swizzled source chunk (halfs)
  const int kbase = grp * 512;

  // B rows: gate-interleaved so each wave's 4 n-tiles are gates i,f,g,o.
  int jr[4];
#pragma unroll
  for (int i = 0; i < 4; ++i) {
    int s = i * 32 + rS;
    jr[i] = (((s >> 4) & 3) << 10) + j0 + (s & 15) + ((s & 64) ? 16 : 0);
  }
  const _Float16* aRow0 = h_prev + (size_t)(b0 + rS) * 1024 + csw;
  const _Float16* aRow1 = h_prev + (size_t)(b0 + 32 + rS) * 1024 + csw;

  const int col = j0 + wn * 16 + l16;
  const _Float16* xrow = Xall + (size_t)(t - 1) * 512 * NG;

  // --- Epilogue operand prefetch (group0 only): hides HBM latency under K-loop
  float xv[2][4][4];
  float cv[2][4];
  if (grp == 0) {
#pragma unroll
    for (int m = 0; m < 2; ++m)
#pragma unroll
      for (int r = 0; r < 4; ++r) {
        int bb = b0 + wm * 32 + m * 16 + quad * 4 + r;
        const _Float16* xb = xrow + (size_t)bb * NG + col;
        xv[m][0][r] = (float)xb[0];
        xv[m][1][r] = (float)xb[1024];
        xv[m][2][r] = (float)xb[2048];
        xv[m][3][r] = (float)xb[3072];
        cv[m][r] = c[(size_t)bb * H_ + col];
      }
  }

  f32x4 acc[2][4] = {};

  auto stage = [&](int buf, int k0) {
    _Float16* sa = &sA[grp][buf][0];
    _Float16* sb = &sB[grp][buf][0];
    cp16(aRow0 + k0, sa + wave * 512);
    cp16(aRow1 + k0, sa + 2048 + wave * 512);
    cp16(Whh + (size_t)jr[0] * 1024 + k0 + csw, sb + wave * 512);
    cp16(Whh + (size_t)jr[1] * 1024 + k0 + csw, sb + 2048 + wave * 512);
    cp16(Whh + (size_t)jr[2] * 1024 + k0 + csw, sb + 4096 + wave * 512);
    cp16(Whh + (size_t)jr[3] * 1024 + k0 + csw, sb + 6144 + wave * 512);
  };
  auto compute = [&](int cur) {
    half8 a[2][2], bfr[2][4];
#pragma unroll
    for (int kk = 0; kk < 2; ++kk) {
#pragma unroll
      for (int m = 0; m < 2; ++m) {
        int row = wm * 32 + m * 16 + l16;
        int ch = ((kk * 4 + quad) ^ (row & 7)) * 8;
        a[kk][m] = *(const half8*)&sA[grp][cur][row * 64 + ch];
      }
#pragma unroll
      for (int n = 0; n < 4; ++n) {
        int row = wn * 64 + n * 16 + l16;
        int ch = ((kk * 4 + quad) ^ (row & 7)) * 8;
        bfr[kk][n] = *(const half8*)&sB[grp][cur][row * 64 + ch];
      }
    }
#pragma unroll
    for (int kk = 0; kk < 2; ++kk)
#pragma unroll
      for (int m = 0; m < 2; ++m)
#pragma unroll
        for (int n = 0; n < 4; ++n)
          acc[m][n] =
              __builtin_amdgcn_mfma_f32_16x16x32_f16(a[kk][m], bfr[kk][n], acc[m][n], 0, 0, 0);
  };

  stage(0, kbase);
  __syncthreads();
  for (int it = 0; it < 7; ++it) {
    stage((it & 1) ^ 1, kbase + (it + 1) * 64);
    compute(it & 1);
    __syncthreads();
  }
  compute(1);  // it=7
  __syncthreads();

  // --- Cross-group reduction through LDS (reuses group0's B buffers, 32 KB).
  // Same (wave,lane)->(row,s) map on both sides; sw XOR breaks the
  // quad-stride-512B 4-way bank conflict into 2-way (free).
  float* red = (float*)&sB[0][0][0];
  if (grp == 1) {
#pragma unroll
    for (int m = 0; m < 2; ++m)
#pragma unroll
      for (int n = 0; n < 4; ++n) {
        int s = wn * 64 + n * 16 + l16;
#pragma unroll
        for (int r = 0; r < 4; ++r) {
          int row = wm * 32 + m * 16 + quad * 4 + r;
          int sw = ((row & 4) << 2) | (row & 8);
          red[row * 128 + (s ^ sw)] = acc[m][n][r];
        }
      }
  }
  __syncthreads();
  if (grp == 0) {
#pragma unroll
    for (int m = 0; m < 2; ++m)
#pragma unroll
      for (int n = 0; n < 4; ++n) {
        int s = wn * 64 + n * 16 + l16;
#pragma unroll
        for (int r = 0; r < 4; ++r) {
          int row = wm * 32 + m * 16 + quad * 4 + r;
          int sw = ((row & 4) << 2) | (row & 8);
          acc[m][n][r] += red[row * 128 + (s ^ sw)];
        }
      }
    // --- Epilogue: acc[m][0..3] = i,f,g,o; Xall/c already in registers.
#pragma unroll
    for (int m = 0; m < 2; ++m) {
#pragma unroll
      for (int r = 0; r < 4; ++r) {
        int bb = b0 + wm * 32 + m * 16 + quad * 4 + r;
        float iv = acc[m][0][r] + xv[m][0][r];
        float fv = acc[m][1][r] + xv[m][1][r];
        float gv = acc[m][2][r] + xv[m][2][r];
        float ov = acc[m][3][r] + xv[m][3][r];
        float ig = sigmoidf_(iv), fg = sigmoidf_(fv), og = sigmoidf_(ov);
        float gg = tanhf(gv);
        size_t ci = (size_t)bb * H_ + col;
        float cn = fg * cv[m][r] + ig * gg;
        c[ci] = cn;
        float hv = og * tanhf(cn);
        h_next[ci] = (_Float16)hv;
        out[(size_t)bb * (T_ * H_) + (size_t)t * H_ + col] = hv;
      }
    }
  }
}

// ---------------------------------------------------------------------------
extern "C" void kernel_launch(void* const* d_in, const int* in_sizes, int n_in,
                              void* d_out, int out_size, void* d_ws, size_t ws_size,
                              hipStream_t stream) {
  (void)in_sizes; (void)n_in; (void)out_size; (void)ws_size;
  const float* dh   = (const float*)d_in[0];
  // d_in[1] ("outputs") is unused by the reference
  const int*   caps = (const int*)d_in[2];
  const float* W_ih = (const float*)d_in[3];
  const float* W_hh = (const float*)d_in[4];
  const float* b_ih = (const float*)d_in[5];
  const float* b_hh = (const float*)d_in[6];
  float* out = (float*)d_out;

  // Workspace layout (~286 MB total)
  char* ws = (char*)d_ws;
  _Float16* Wx116 = (_Float16*)(ws);                 //   8,388,608
  _Float16* Whh16 = (_Float16*)(ws + 8388608);       //   8,388,608
  _Float16* Wp    = (_Float16*)(ws + 16777216);      //   8,388,608
  _Float16* dh16  = (_Float16*)(ws + 25165824);      //  50,331,648
  _Float16* pld16 = (_Float16*)(ws + 75497472);      //   1,048,576
  float*    Xc    = (float*)   (ws + 76546048);      //   8,388,608
  _Float16* Xall  = (_Float16*)(ws + 84934656);      // 197,132,288 (47*512*4096 f16)
  _Float16* hA    = (_Float16*)(ws + 282066944);     //   1,048,576
  _Float16* hB    = (_Float16*)(ws + 283115520);     //   1,048,576
  float*    c     = (float*)   (ws + 284164096);     //   2,097,152  (end ~286.3 MB)

  prep_w<<<49152, 256, 0, stream>>>(W_ih, W_hh, Wx116, Whh16, Wp);
  pool_conv<<<2048, 256, 0, stream>>>(dh, caps, dh16, pld16);
  init_zero<<<2048, 256, 0, stream>>>(hA, c, out);
  gemm_pool<<<dim3(32, 8), 256, 0, stream>>>(pld16, Wp, b_ih, b_hh, Xc);
  // A = dh16 rows from t=1 onward: dh16 + 512*1024 elements, [24064 x 1024] f16
  gemm_x<<<dim3(32, 188), 256, 0, stream>>>(dh16 + 524288, Wx116, Xc, Xall);
  for (int t = 1; t < T_; ++t) {
    const _Float16* hp = (t & 1) ? hA : hB;
    _Float16*       hn = (t & 1) ? hB : hA;
    lstm_step<<<dim3(32, 8), 512, 0, stream>>>(Whh16, Xall, hp, hn, c, out, t);
  }
}